// Round 1
// baseline (456.459 us; speedup 1.0000x reference)
//
#include <hip/hip_runtime.h>
#include <math.h>

// Problem constants
#define BB 256
#define CC 16
#define TT 9000          // samples per channel
#define DT 300           // crop length
#define KK 64            // crops per channel
#define NB 35            // band bins: rfft bins 7..41
#define KMIN 7
#define NPAIR (KK * NB)  // 2240 outputs per (b,c)
#define NCH (BB * CC)    // 4096 channels

// Twiddle table layout in d_ws: per (t, wave): 5 float4 = 20 floats
//   [c0,s0, c1,s1, ..., c8,s8, pad, pad]  (9 cos/sin pairs for that wave's bins)
// float4 index: (t*4 + w)*5 + q          total 300*4*5 = 6000 float4 = 96 KB
__global__ void build_table(float4* __restrict__ tab) {
    int i = blockIdx.x * blockDim.x + threadIdx.x;
    if (i >= DT * 4 * 5) return;
    int q = i % 5;
    int w = (i / 5) % 4;
    int t = i / 20;
    float v[4];
#pragma unroll
    for (int e = 0; e < 4; ++e) {
        int slot = q * 4 + e;   // 0..19
        int jloc = slot >> 1;   // 0..9 (9 = pad, never read)
        int comp = slot & 1;    // 0=cos, 1=sin
        int j = w * 9 + jloc;
        if (j > NB - 1) j = NB - 1;           // wave 3 duplicates bin 34 (harmless)
        int k = j + KMIN;                     // rfft bin 7..41
        int m = (k * t) % DT;                 // exact integer phase reduction
        double ang = 6.283185307179586 * (double)m / (double)DT;
        v[e] = comp ? (float)sin(ang) : (float)cos(ang);
    }
    tab[i] = make_float4(v[0], v[1], v[2], v[3]);
}

__global__ __launch_bounds__(256) void st_power(
        const float* __restrict__ input,     // [BB*CC, TT]
        const int* __restrict__ offsets,     // [BB*CC, KK]
        const float4* __restrict__ tab,      // twiddle table (see above)
        float* __restrict__ out) {           // [BB*CC, KK, NB]
    __shared__ __align__(16) float sig[TT];
    __shared__ __align__(16) float pw[NPAIR];
    __shared__ float rsum[KK];
    __shared__ int offs[KK];

    const int bc = blockIdx.x;
    const int tid = threadIdx.x;

    // Stage channel signal into LDS with float4 loads (base is 16B-aligned:
    // bc*9000*4B = bc*36000, 36000 % 16 == 0).
    const float4* src = (const float4*)(input + (size_t)bc * TT);
    float4* dst = (float4*)sig;
    for (int i = tid; i < TT / 4; i += 256) dst[i] = src[i];
    if (tid < KK) offs[tid] = offsets[bc * KK + tid];
    __syncthreads();

    // lane = crop, wave = group of 9 contiguous bins
    const int w = __builtin_amdgcn_readfirstlane(tid >> 6);  // scalar wave id
    const int lane = tid & 63;
    const int off = offs[lane];
    const float* sp = sig + off;

    float aR[9], aI[9];
#pragma unroll
    for (int i = 0; i < 9; ++i) { aR[i] = 0.f; aI[i] = 0.f; }

#pragma unroll 2
    for (int t = 0; t < DT; ++t) {
        float x = sp[t];  // per-lane random offset -> LDS read
        const float4* p = tab + (t * 4 + w) * 5;  // uniform addr -> s_load
        float4 q0 = p[0], q1 = p[1], q2 = p[2], q3 = p[3], q4 = p[4];
        aR[0] = fmaf(x, q0.x, aR[0]); aI[0] = fmaf(x, q0.y, aI[0]);
        aR[1] = fmaf(x, q0.z, aR[1]); aI[1] = fmaf(x, q0.w, aI[1]);
        aR[2] = fmaf(x, q1.x, aR[2]); aI[2] = fmaf(x, q1.y, aI[2]);
        aR[3] = fmaf(x, q1.z, aR[3]); aI[3] = fmaf(x, q1.w, aI[3]);
        aR[4] = fmaf(x, q2.x, aR[4]); aI[4] = fmaf(x, q2.y, aI[4]);
        aR[5] = fmaf(x, q2.z, aR[5]); aI[5] = fmaf(x, q2.w, aI[5]);
        aR[6] = fmaf(x, q3.x, aR[6]); aI[6] = fmaf(x, q3.y, aI[6]);
        aR[7] = fmaf(x, q3.z, aR[7]); aI[7] = fmaf(x, q3.w, aI[7]);
        aR[8] = fmaf(x, q4.x, aR[8]); aI[8] = fmaf(x, q4.y, aI[8]);
    }

    // Power into LDS [crop][bin]; wave 3 writes bin 34 twice with same value.
#pragma unroll
    for (int i = 0; i < 9; ++i) {
        int j = w * 9 + i;
        if (j > NB - 1) j = NB - 1;
        pw[lane * NB + j] = aR[i] * aR[i] + aI[i] * aI[i];
    }
    __syncthreads();

    // Per-crop band sum -> reciprocal
    if (tid < KK) {
        float s = 0.f;
#pragma unroll
        for (int j = 0; j < NB; ++j) s += pw[tid * NB + j];
        rsum[tid] = 1.0f / s;
    }
    __syncthreads();

    // Normalized, coalesced store
    float* o = out + (size_t)bc * NPAIR;
    for (int idx = tid; idx < NPAIR; idx += 256) {
        int k = idx / NB;
        o[idx] = pw[idx] * rsum[k];
    }
}

extern "C" void kernel_launch(void* const* d_in, const int* in_sizes, int n_in,
                              void* d_out, int out_size, void* d_ws, size_t ws_size,
                              hipStream_t stream) {
    const float* input = (const float*)d_in[0];   // [256,16,9000] fp32
    const int* offsets = (const int*)d_in[1];     // [256,16,64] int32
    float* out = (float*)d_out;                   // [256,16,64,35] fp32
    float4* tab = (float4*)d_ws;                  // 96000 B twiddle table

    // Rebuild table every call (d_ws is re-poisoned before each timed launch).
    int nt4 = DT * 4 * 5;  // 6000 float4
    build_table<<<(nt4 + 255) / 256, 256, 0, stream>>>(tab);
    st_power<<<NCH, 256, 0, stream>>>(input, offsets, tab, out);
}

// Round 2
// 247.703 us; speedup vs baseline: 1.8428x; 1.8428x over previous
//
#include <hip/hip_runtime.h>
#include <math.h>

// Problem constants
#define TT 9000          // samples per channel
#define DT 300           // crop length
#define KK 64            // crops per channel
#define NB 35            // band bins: rfft bins 7..41 (freqs 0.1*i, band 40/60..250/60)
#define KMIN 7
#define NCH 4096         // B*C channels
#define NPAIR (KK * NB)  // 2240 outputs per channel

// GEMM shape per channel: C[64 x 96] = A[64 x 320] * W[320 x 96]
//   A[m][k] = sig[off_m + k]          (k >= 300 multiplied by zero W rows)
//   W cols: n-tile 0..2 -> cos_j, j = nt*16 + (n%16), j<=34 else 0
//           n-tile 3..5 -> sin_j likewise
// 16x16x32 bf16 MFMA, 10 K-steps, 6 N-tiles, 4 waves = 4 M-tiles.

typedef __bf16 bf16;
typedef __attribute__((ext_vector_type(8))) __bf16 bf16x8;
typedef __attribute__((ext_vector_type(4))) float f32x4;

#define NFRAG_ELEMS (10 * 6 * 64 * 8)   // 30720 bf16 = 61440 B in d_ws

// W table in B-fragment order: flat idx ((kstep*6 + nt)*64 + lane)*8 + j
// B-frag layout (16x16x32): lane l holds B[k = kstep*32 + (l>>4)*8 + j][n = l&15]
__global__ void build_w(bf16* __restrict__ tab) {
    int i = blockIdx.x * blockDim.x + threadIdx.x;
    if (i >= NFRAG_ELEMS) return;
    int j    = i & 7;
    int l    = (i >> 3) & 63;
    int f    = i >> 9;           // frag index = kstep*6 + nt
    int nt   = f % 6;
    int ks   = f / 6;
    int quad = l >> 4;
    int c    = l & 15;
    int k    = ks * 32 + quad * 8 + j;   // time index 0..319
    int jf   = (nt % 3) * 16 + c;        // band bin index 0..47
    float v = 0.0f;
    if (jf <= NB - 1 && k < DT) {
        int bin = jf + KMIN;                       // rfft bin 7..41
        int ph  = (bin * k) % DT;                  // exact integer phase
        double ang = 6.283185307179586 * (double)ph / (double)DT;
        v = (nt >= 3) ? (float)sin(ang) : (float)cos(ang);
    }
    tab[i] = (bf16)v;
}

__global__ __launch_bounds__(256, 4) void st_mfma(
        const float* __restrict__ input,    // [NCH, TT] fp32
        const int*   __restrict__ offsets,  // [NCH, KK] int32
        const bf16*  __restrict__ tab,      // W in B-frag order
        float*       __restrict__ out) {    // [NCH, KK, NB] fp32
    __shared__ __align__(16) float sig[TT + 32];  // +32 pad: reads reach off+319 <= 9019
    __shared__ int offs[KK];

    const int bc  = blockIdx.x;
    const int tid = threadIdx.x;

    // Stage channel into LDS (coalesced float4; base 36000B per channel, 16B-aligned)
    const float4* src = (const float4*)(input + (size_t)bc * TT);
    float4* dst = (float4*)sig;
    for (int i = tid; i < TT / 4; i += 256) dst[i] = src[i];
    if (tid < 32) sig[TT + tid] = 0.0f;
    if (tid < KK) offs[tid] = offsets[bc * KK + tid];
    __syncthreads();

    const int w    = tid >> 6;    // wave = M-tile (16 crops)
    const int lane = tid & 63;
    const int quad = lane >> 4;
    const int c    = lane & 15;

    // A-frag: lane holds A[m = lane&15][k = kstep*32 + quad*8 + j], j=0..7
    const int   off = offs[w * 16 + c];
    const float* sp = sig + off + quad * 8;

    f32x4 acc[6];
#pragma unroll
    for (int nt = 0; nt < 6; ++nt) acc[nt] = (f32x4){0.f, 0.f, 0.f, 0.f};

    const bf16x8* wt = (const bf16x8*)tab;

#pragma unroll
    for (int ks = 0; ks < 10; ++ks) {
        const float* p = sp + ks * 32;
        bf16x8 a;
#pragma unroll
        for (int j = 0; j < 8; ++j) a[j] = (bf16)p[j];
#pragma unroll
        for (int nt = 0; nt < 6; ++nt) {
            bf16x8 b = wt[(ks * 6 + nt) * 64 + lane];
            acc[nt] = __builtin_amdgcn_mfma_f32_16x16x32_bf16(a, b, acc[nt], 0, 0, 0);
        }
    }

    // Epilogue, all in registers. C/D layout: col = lane&15, row = quad*4 + r.
    // cos_j in acc[i], sin_j in acc[i+3] (same lane), j = i*16 + c.
    float* o = out + (size_t)bc * NPAIR;
#pragma unroll
    for (int r = 0; r < 4; ++r) {
        float p0 = acc[0][r] * acc[0][r] + acc[3][r] * acc[3][r];  // j = c
        float p1 = acc[1][r] * acc[1][r] + acc[4][r] * acc[4][r];  // j = 16+c
        float p2 = acc[2][r] * acc[2][r] + acc[5][r] * acc[5][r];  // j = 32+c (c<=2)
        float s = p0 + p1 + ((c <= 2) ? p2 : 0.0f);
        // band sum: reduce across the 16 lanes of this quad (xor masks stay in-quad)
#pragma unroll
        for (int d = 1; d < 16; d <<= 1) s += __shfl_xor(s, d, 64);
        float rinv = 1.0f / s;
        int crop = w * 16 + quad * 4 + r;
        float* oc = o + crop * NB;
        oc[c] = p0 * rinv;
        oc[16 + c] = p1 * rinv;
        if (c <= 2) oc[32 + c] = p2 * rinv;
    }
}

extern "C" void kernel_launch(void* const* d_in, const int* in_sizes, int n_in,
                              void* d_out, int out_size, void* d_ws, size_t ws_size,
                              hipStream_t stream) {
    const float* input   = (const float*)d_in[0];  // [256,16,9000] fp32
    const int*   offsets = (const int*)d_in[1];    // [256,16,64] int32
    float*       out     = (float*)d_out;          // [256,16,64,35] fp32
    bf16*        tab     = (bf16*)d_ws;            // 61440 B

    // d_ws is re-poisoned before every timed launch -> rebuild table each call.
    build_w<<<(NFRAG_ELEMS + 255) / 256, 256, 0, stream>>>(tab);
    st_mfma<<<NCH, 256, 0, stream>>>(input, offsets, tab, out);
}

// Round 3
// 241.802 us; speedup vs baseline: 1.8877x; 1.0244x over previous
//
#include <hip/hip_runtime.h>
#include <math.h>

// Problem constants
#define TT 9000          // samples per channel
#define DT 300           // crop length
#define KK 64            // crops per channel
#define NB 35            // band bins: rfft bins 7..41 (freqs 0.1*i, band 40/60..250/60)
#define KMIN 7
#define NCH 4096         // B*C channels
#define NPAIR (KK * NB)  // 2240 outputs per channel

// GEMM shape per channel: C[64 x 96] = A[64 x 320] * W[320 x 96]
//   A[m][k] = sig[off_m + k]          (k >= 300 multiplied by zero W rows)
//   W cols: n-tile 0..2 -> cos_j, j = nt*16 + (n%16), j<=34 else 0
//           n-tile 3..5 -> sin_j likewise
// 16x16x32 bf16 MFMA, 10 K-steps, 6 N-tiles, 4 waves = 4 M-tiles.
// Mean-subtraction is a no-op for bins>=1; forward-norm 1/300 cancels in the
// unit-sum normalization.

typedef __bf16 bf16;
typedef __attribute__((ext_vector_type(8))) __bf16 bf16x8;
typedef __attribute__((ext_vector_type(4))) float f32x4;

#define NFRAG_ELEMS (10 * 6 * 64 * 8)   // 30720 bf16 = 61440 B in d_ws

// W table in B-fragment order: flat idx ((kstep*6 + nt)*64 + lane)*8 + j
// B-frag layout (16x16x32): lane l holds B[k = kstep*32 + (l>>4)*8 + j][n = l&15]
__global__ void build_w(bf16* __restrict__ tab) {
    int i = blockIdx.x * blockDim.x + threadIdx.x;
    if (i >= NFRAG_ELEMS) return;
    int j    = i & 7;
    int l    = (i >> 3) & 63;
    int f    = i >> 9;           // frag index = kstep*6 + nt
    int nt   = f % 6;
    int ks   = f / 6;
    int quad = l >> 4;
    int c    = l & 15;
    int k    = ks * 32 + quad * 8 + j;   // time index 0..319
    int jf   = (nt % 3) * 16 + c;        // band bin index 0..47
    float v = 0.0f;
    if (jf <= NB - 1 && k < DT) {
        int bin = jf + KMIN;                       // rfft bin 7..41
        int ph  = (bin * k) % DT;                  // exact integer phase
        float ang = 0.02094395102393195f * (float)ph;  // 2*pi/300 * ph, ph<300
        v = (nt >= 3) ? sinf(ang) : cosf(ang);     // fp32 plenty for bf16 target
    }
    tab[i] = (bf16)v;
}

__global__ __launch_bounds__(256, 4) void st_mfma(
        const float* __restrict__ input,    // [NCH, TT] fp32
        const int*   __restrict__ offsets,  // [NCH, KK] int32
        const bf16*  __restrict__ tab,      // W in B-frag order
        float*       __restrict__ out) {    // [NCH, KK, NB] fp32
    __shared__ __align__(16) float sig[TT + 32];  // +32 pad: reads reach off+319 <= 9019
    __shared__ int offs[KK];

    const int bc  = blockIdx.x;
    const int tid = threadIdx.x;

    // Stage channel into LDS (coalesced float4; base 36000B per channel, 16B-aligned)
    const float4* src = (const float4*)(input + (size_t)bc * TT);
    float4* dst = (float4*)sig;
#pragma unroll
    for (int i = 0; i < 9; ++i) {        // 9*256 = 2304 >= 2250
        int idx = tid + i * 256;
        if (idx < TT / 4) dst[idx] = src[idx];
    }
    if (tid < 32) sig[TT + tid] = 0.0f;
    if (tid < KK) offs[tid] = offsets[bc * KK + tid];
    __syncthreads();

    const int w    = tid >> 6;    // wave = M-tile (16 crops)
    const int lane = tid & 63;
    const int quad = lane >> 4;
    const int c    = lane & 15;

    // A-frag: lane holds A[m = lane&15][k = kstep*32 + quad*8 + j], j=0..7
    const int   off = offs[w * 16 + c];
    const float* sp = sig + off + quad * 8;

    const bf16x8* wt = (const bf16x8*)tab;

    f32x4 acc[6];
#pragma unroll
    for (int nt = 0; nt < 6; ++nt) acc[nt] = (f32x4){0.f, 0.f, 0.f, 0.f};

    // ---- software pipeline: prefetch next k-step's A samples + B frags ----
    float  a_f[8];
    bf16x8 bb[6];
#pragma unroll
    for (int j = 0; j < 8; ++j) a_f[j] = sp[j];
#pragma unroll
    for (int nt = 0; nt < 6; ++nt) bb[nt] = wt[nt * 64 + lane];

#pragma unroll
    for (int ks = 0; ks < 10; ++ks) {
        // convert current A to bf16 fragment
        bf16x8 a;
#pragma unroll
        for (int j = 0; j < 8; ++j) a[j] = (bf16)a_f[j];

        // issue next iteration's loads BEFORE consuming current B frags:
        // these stay in flight across the 6 MFMAs below (no dependency).
        float  a_n[8];
        bf16x8 bn[6];
        if (ks < 9) {
            const float* p = sp + (ks + 1) * 32;
#pragma unroll
            for (int j = 0; j < 8; ++j) a_n[j] = p[j];
#pragma unroll
            for (int nt = 0; nt < 6; ++nt) bn[nt] = wt[((ks + 1) * 6 + nt) * 64 + lane];
        }

#pragma unroll
        for (int nt = 0; nt < 6; ++nt)
            acc[nt] = __builtin_amdgcn_mfma_f32_16x16x32_bf16(a, bb[nt], acc[nt], 0, 0, 0);

        if (ks < 9) {
#pragma unroll
            for (int j = 0; j < 8; ++j) a_f[j] = a_n[j];
#pragma unroll
            for (int nt = 0; nt < 6; ++nt) bb[nt] = bn[nt];
        }
    }

    // Epilogue, all in registers. C/D layout: col = lane&15, row = quad*4 + r.
    // cos_j in acc[i], sin_j in acc[i+3] (same lane), j = i*16 + c.
    float* o = out + (size_t)bc * NPAIR;
#pragma unroll
    for (int r = 0; r < 4; ++r) {
        float p0 = acc[0][r] * acc[0][r] + acc[3][r] * acc[3][r];  // j = c
        float p1 = acc[1][r] * acc[1][r] + acc[4][r] * acc[4][r];  // j = 16+c
        float p2 = acc[2][r] * acc[2][r] + acc[5][r] * acc[5][r];  // j = 32+c (c<=2)
        float s = p0 + p1 + ((c <= 2) ? p2 : 0.0f);
        // band sum: reduce across the 16 lanes of this quad (xor masks stay in-quad)
#pragma unroll
        for (int d = 1; d < 16; d <<= 1) s += __shfl_xor(s, d, 64);
        float rinv = 1.0f / s;
        int crop = w * 16 + quad * 4 + r;
        float* oc = o + crop * NB;
        oc[c] = p0 * rinv;
        oc[16 + c] = p1 * rinv;
        if (c <= 2) oc[32 + c] = p2 * rinv;
    }
}

extern "C" void kernel_launch(void* const* d_in, const int* in_sizes, int n_in,
                              void* d_out, int out_size, void* d_ws, size_t ws_size,
                              hipStream_t stream) {
    const float* input   = (const float*)d_in[0];  // [256,16,9000] fp32
    const int*   offsets = (const int*)d_in[1];    // [256,16,64] int32
    float*       out     = (float*)d_out;          // [256,16,64,35] fp32
    bf16*        tab     = (bf16*)d_ws;            // 61440 B

    // d_ws is re-poisoned before every timed launch -> rebuild table each call.
    build_w<<<(NFRAG_ELEMS + 255) / 256, 256, 0, stream>>>(tab);
    st_mfma<<<NCH, 256, 0, stream>>>(input, offsets, tab, out);
}